// Round 9
// baseline (897.178 us; speedup 1.0000x reference)
//
#include <hip/hip_runtime.h>
#include <hip/hip_bf16.h>
#include <math.h>

#define D_ 512
#define K_ 8
#define L_ 64
#define Q_ 4096
#define C_ 4096
#define N_ (C_ * K_)   // 32768 rows of P viewed as [N][D]

typedef short short8 __attribute__((ext_vector_type(8)));
typedef float f32x4 __attribute__((ext_vector_type(4)));

static __device__ __forceinline__ void split2(float v, unsigned short& h, unsigned short& l) {
    __hip_bfloat16 hh = __float2bfloat16(v);
    float r = v - __bfloat162float(hh);
    __hip_bfloat16 ll = __float2bfloat16(r);
    h = *reinterpret_cast<unsigned short*>(&hh);
    l = *reinterpret_cast<unsigned short*>(&ll);
}

#define ASYNC_COPY16(gp, lp)                                                        \
    __builtin_amdgcn_global_load_lds((const __attribute__((address_space(1))) void*)(gp), \
                                     (__attribute__((address_space(3))) void*)(lp), \
                                     16, 0, 0)

// ---------------------------------------------------------------------------
// Fused prep: M-transpose tiles (blocks 0..511), class split x4 (512..2559),
// query split x4 (2560..4607). All fp32 -> bf16 hi/lo.
// ---------------------------------------------------------------------------
__global__ void fused_prep(const float* __restrict__ M,
                           const float* __restrict__ class_v,
                           const float* __restrict__ query_v,
                           unsigned short* __restrict__ Mh, unsigned short* __restrict__ Ml,
                           unsigned short* __restrict__ Chh, unsigned short* __restrict__ Cll,
                           unsigned short* __restrict__ Qh, unsigned short* __restrict__ Ql) {
    __shared__ float t[64 * 65];
    const int b = blockIdx.x;
    const int tid = threadIdx.x;
    if (b < 512) {
        // M [512 i][4096 t] (t=j*8+k) -> Mh/Ml [k*512+j][i]
        const int t0 = (b & 63) * 64;
        const int i0 = (b >> 6) * 64;
#pragma unroll
        for (int it = 0; it < 16; ++it) {
            int idx = tid + it * 256;
            int ri = idx >> 6, tc = idx & 63;
            t[tc * 65 + ri] = M[(size_t)(i0 + ri) * 4096 + t0 + tc];
        }
        __syncthreads();
        const int j0 = t0 >> 3;
#pragma unroll
        for (int it = 0; it < 16; ++it) {
            int odx = tid + it * 256;
            int tl = odx >> 6, ic = odx & 63;
            int n2 = (tl & 7) * 512 + j0 + (tl >> 3);
            size_t o = (size_t)n2 * 512 + i0 + ic;
            split2(t[tl * 65 + ic], Mh[o], Ml[o]);
        }
    } else if (b < 2560) {
        int i4 = ((b - 512) * 256 + tid) * 4;
        float4 v = *(const float4*)&class_v[i4];
        ushort4 h, l;
        split2(v.x, h.x, l.x);
        split2(v.y, h.y, l.y);
        split2(v.z, h.z, l.z);
        split2(v.w, h.w, l.w);
        *(ushort4*)&Chh[i4] = h;
        *(ushort4*)&Cll[i4] = l;
    } else {
        int i4 = ((b - 2560) * 256 + tid) * 4;
        float4 v = *(const float4*)&query_v[i4];
        ushort4 h, l;
        split2(v.x, h.x, l.x);
        split2(v.y, h.y, l.y);
        split2(v.z, h.z, l.z);
        split2(v.w, h.w, l.w);
        *(ushort4*)&Qh[i4] = h;
        *(ushort4*)&Ql[i4] = l;
    }
}

// ---------------------------------------------------------------------------
// 128x128 NT-GEMM core, counted-vmcnt schedule (r3/r8 measured-best).
// A via double-buffered LDS (global_load_lds, swizzled source); B direct
// global->VGPR with plain C++ loads. Per iter: stage A(t+1)->nxt then load
// B(t+1); MFMA on cur; end: vmcnt(4) (A landed, B in flight) + s_barrier.
// No vmcnt(0) in the main loop. bf16x3 term-reordered.
// ---------------------------------------------------------------------------
#define BM1 128
#define BN1 128
#define BNW1 32
#define BKK1 32

__device__ __forceinline__ void mfma_core_nt(
    const unsigned short* __restrict__ Agh, const unsigned short* __restrict__ Agl,
    const unsigned short* __restrict__ Bgh, const unsigned short* __restrict__ Bgl,
    int lda, int ldb, int kd, int m0, int n0,
    unsigned short (*Ahb)[BM1 * BKK1], unsigned short (*Alb)[BM1 * BKK1],
    f32x4 acc[8][2]) {
    const int tid = threadIdx.x;
    const int lane = tid & 63;
    const int wid = tid >> 6;
    const int fr = lane & 15;
    const int fq = lane >> 4;
    const int co = (fq ^ ((fr >> 1) & 3)) * 8;

    const unsigned short* bh0 = Bgh + (size_t)(n0 + wid * BNW1 + fr) * ldb + fq * 8;
    const unsigned short* bl0 = Bgl + (size_t)(n0 + wid * BNW1 + fr) * ldb + fq * 8;

    short8 bh[2][2], bl[2][2];

#define STAGE_A(k0_, buf_)                                                      \
    {                                                                           \
        _Pragma("unroll")                                                       \
        for (int h = 0; h < 2; ++h) {                                           \
            const int i2 = h * 256 + tid;                                       \
            const int r = i2 >> 2;                                              \
            const int cg = (i2 & 3) ^ ((r >> 1) & 3);                           \
            const int ldsoff = (h * 256 + (tid & ~63)) * 8;                     \
            const size_t go = (size_t)(m0 + r) * lda + (k0_) + cg * 8;          \
            ASYNC_COPY16(Agh + go, &Ahb[buf_][ldsoff]);                         \
            ASYNC_COPY16(Agl + go, &Alb[buf_][ldsoff]);                         \
        }                                                                       \
    }
#define LOAD_B(k0_, g_)                                                         \
    bh[g_][0] = *(const short8*)(bh0 + (k0_));                                  \
    bh[g_][1] = *(const short8*)(bh0 + 16 * (size_t)ldb + (k0_));               \
    bl[g_][0] = *(const short8*)(bl0 + (k0_));                                  \
    bl[g_][1] = *(const short8*)(bl0 + 16 * (size_t)ldb + (k0_));

    const int niter = kd / BKK1;   // 16 (kd inlined constant)

    // Prologue: stage A(0)->buf0 (issue FIRST), then B(0).
    STAGE_A(0, 0)
    asm volatile("" ::: "memory");   // pin issue order: A-stage before B-loads
    LOAD_B(0, 0)
    asm volatile("s_waitcnt vmcnt(4)" ::: "memory");   // A(0) in LDS; B(0) in flight
    __builtin_amdgcn_sched_barrier(0);
    asm volatile("s_barrier" ::: "memory");

#pragma unroll
    for (int it = 0; it < niter; ++it) {
        const int cur = it & 1, nxt = cur ^ 1;
        if (it + 1 < niter) {
            STAGE_A((it + 1) * BKK1, nxt)
        }
        asm volatile("" ::: "memory");   // pin issue order: A-stage before B-loads
        if (it + 1 < niter) {
            LOAD_B((it + 1) * BKK1, nxt)
        }
#pragma unroll
        for (int mi = 0; mi < 8; ++mi) {
            const short8 ah = *(const short8*)&Ahb[cur][(mi * 16 + fr) * BKK1 + co];
            const short8 al = *(const short8*)&Alb[cur][(mi * 16 + fr) * BKK1 + co];
#pragma unroll
            for (int ni = 0; ni < 2; ++ni)
                acc[mi][ni] = __builtin_amdgcn_mfma_f32_16x16x32_bf16(ah, bh[cur][ni], acc[mi][ni], 0, 0, 0);
#pragma unroll
            for (int ni = 0; ni < 2; ++ni)
                acc[mi][ni] = __builtin_amdgcn_mfma_f32_16x16x32_bf16(ah, bl[cur][ni], acc[mi][ni], 0, 0, 0);
#pragma unroll
            for (int ni = 0; ni < 2; ++ni)
                acc[mi][ni] = __builtin_amdgcn_mfma_f32_16x16x32_bf16(al, bh[cur][ni], acc[mi][ni], 0, 0, 0);
        }
        if (it + 1 < niter) {
            // A(it+1) (oldest 4 outstanding) landed; B(it+1) stays in flight.
            asm volatile("s_waitcnt vmcnt(4)" ::: "memory");
            __builtin_amdgcn_sched_barrier(0);
            asm volatile("s_barrier" ::: "memory");
        }
    }
#undef STAGE_A
#undef LOAD_B
}

// ---------------------------------------------------------------------------
// bilinear: other[q][c] = sb + sum_k sw[k]*relu( sum_j query[q,j]*P[c*8+k][j] )
// Natural grid order (q-fastest): 32 consecutive blocks share one B-panel.
// launch_bounds (256,5): VGPR 64 and LDS 32KB allow 5 blocks/CU (160KB pool
// exactly); r8 ran at a self-imposed 4-block cap (Occupancy 43%).
// ---------------------------------------------------------------------------
__launch_bounds__(256, 5)
__global__ void bilinear_mfma(const unsigned short* __restrict__ Qh,
                              const unsigned short* __restrict__ Ql,
                              const unsigned short* __restrict__ Ph,
                              const unsigned short* __restrict__ Pl,
                              const float* __restrict__ sw,
                              const float* __restrict__ sb,
                              float* __restrict__ other) {
    __shared__ __attribute__((aligned(16))) unsigned short Ahb[2][BM1 * BKK1];
    __shared__ __attribute__((aligned(16))) unsigned short Alb[2][BM1 * BKK1];
    const int tid = threadIdx.x;
    const int lane = tid & 63;
    const int wid = tid >> 6;
    const int fr = lane & 15;
    const int fq = lane >> 4;
    f32x4 acc[8][2] = {};
    const int q0 = blockIdx.x * BM1;   // q-fastest
    const int n0 = blockIdx.y * BN1;   // over N = C*K
    mfma_core_nt(Qh, Ql, Ph, Pl, D_, D_, D_, q0, n0, Ahb, Alb, acc);
    const float wk = sw[lane & 7];
    const float bias = sb[0];
#pragma unroll
    for (int mi = 0; mi < 8; ++mi)
#pragma unroll
        for (int ni = 0; ni < 2; ++ni)
#pragma unroll
            for (int r = 0; r < 4; ++r) {
                float v2 = wk * fmaxf(acc[mi][ni][r], 0.f);
                v2 += __shfl_xor(v2, 1);
                v2 += __shfl_xor(v2, 2);
                v2 += __shfl_xor(v2, 4);
                if ((lane & 7) == 0) {
                    int q = q0 + mi * 16 + fq * 4 + r;
                    int c = (n0 + wid * BNW1 + ni * 16 + fr) >> 3;
                    other[(size_t)q * C_ + c] = v2 + bias;
                }
            }
}

// ---------------------------------------------------------------------------
// 8-phase 256x256 MFMA NT-GEMM core (for the small L2-resident GEMMs).
// ---------------------------------------------------------------------------
#define OPS_ 8192
#define BUFS_ (4 * OPS_)

__device__ __forceinline__ void mfma_core8(
    const unsigned short* __restrict__ Agh, const unsigned short* __restrict__ Agl,
    const unsigned short* __restrict__ Bgh, const unsigned short* __restrict__ Bgl,
    const int lda, const int ldb, const int kd, const int m0, const int n0,
    unsigned short* Lds, f32x4 acc[8][4]) {
    const int tid = threadIdx.x;
    const int lane = tid & 63;
    const int wid = tid >> 6;
    const int fr = lane & 15;
    const int co = ((lane >> 4) ^ ((fr >> 1) & 3)) * 8;
    const int wm = (wid >> 2) * 128;
    const int wn = (wid & 3) * 64;
    const int nt = kd >> 5;
    const int aoff = (wm + fr) * 32 + co;
    const int boff = (wn + fr) * 32 + co;

#define STAGE8(k0_, buf_)                                                              \
    {                                                                                  \
        _Pragma("unroll")                                                              \
        for (int h_ = 0; h_ < 2; ++h_) {                                               \
            const int i2_ = h_ * 512 + tid;                                            \
            const int r_ = i2_ >> 2;                                                   \
            const int cg_ = (i2_ & 3) ^ ((r_ >> 1) & 3);                               \
            unsigned short* lp_ = Lds + (buf_) * BUFS_ + (h_ * 512 + (tid & ~63)) * 8; \
            const size_t ga_ = (size_t)(m0 + r_) * lda + (k0_) + cg_ * 8;              \
            const size_t gb_ = (size_t)(n0 + r_) * ldb + (k0_) + cg_ * 8;              \
            ASYNC_COPY16(Agh + ga_, lp_);                                              \
            ASYNC_COPY16(Agl + ga_, lp_ + OPS_);                                       \
            ASYNC_COPY16(Bgh + gb_, lp_ + 2 * OPS_);                                   \
            ASYNC_COPY16(Bgl + gb_, lp_ + 3 * OPS_);                                   \
        }                                                                              \
    }

#define QUAD(MH, NH)                                                                         \
    _Pragma("unroll")                                                                        \
    for (int i_ = 0; i_ < 4; ++i_) {                                                         \
        _Pragma("unroll")                                                                    \
        for (int j_ = 0; j_ < 2; ++j_) {                                                     \
            f32x4& a_ = acc[(MH) * 4 + i_][(NH) * 2 + j_];                                   \
            a_ = __builtin_amdgcn_mfma_f32_16x16x32_bf16(ah[i_], bhv[(NH) * 2 + j_], a_, 0, 0, 0); \
        }                                                                                    \
    }                                                                                        \
    _Pragma("unroll")                                                                        \
    for (int i_ = 0; i_ < 4; ++i_) {                                                         \
        _Pragma("unroll")                                                                    \
        for (int j_ = 0; j_ < 2; ++j_) {                                                     \
            f32x4& a_ = acc[(MH) * 4 + i_][(NH) * 2 + j_];                                   \
            a_ = __builtin_amdgcn_mfma_f32_16x16x32_bf16(ah[i_], blv[(NH) * 2 + j_], a_, 0, 0, 0); \
        }                                                                                    \
    }                                                                                        \
    _Pragma("unroll")                                                                        \
    for (int i_ = 0; i_ < 4; ++i_) {                                                         \
        _Pragma("unroll")                                                                    \
        for (int j_ = 0; j_ < 2; ++j_) {                                                     \
            f32x4& a_ = acc[(MH) * 4 + i_][(NH) * 2 + j_];                                   \
            a_ = __builtin_amdgcn_mfma_f32_16x16x32_bf16(al[i_], bhv[(NH) * 2 + j_], a_, 0, 0, 0); \
        }                                                                                    \
    }

    STAGE8(0, 0)
    STAGE8(32, 1)
    asm volatile("s_waitcnt vmcnt(8)" ::: "memory");
    __builtin_amdgcn_sched_barrier(0);
    __builtin_amdgcn_s_barrier();

#pragma unroll 2
    for (int t = 0; t < nt; ++t) {
        const int cur = t & 1;
        const unsigned short* Lc = Lds + cur * BUFS_;
        short8 ah[4], al[4], bhv[4], blv[4];

#pragma unroll
        for (int i = 0; i < 4; ++i) {
            ah[i] = *(const short8*)(Lc + aoff + i * 512);
            al[i] = *(const short8*)(Lc + OPS_ + aoff + i * 512);
        }
#pragma unroll
        for (int j = 0; j < 2; ++j) {
            bhv[j] = *(const short8*)(Lc + 2 * OPS_ + boff + j * 512);
            blv[j] = *(const short8*)(Lc + 3 * OPS_ + boff + j * 512);
        }
        __builtin_amdgcn_s_barrier();
        asm volatile("s_waitcnt lgkmcnt(0)" ::: "memory");
        __builtin_amdgcn_sched_barrier(0);
        __builtin_amdgcn_s_setprio(1);
        QUAD(0, 0)
        __builtin_amdgcn_s_setprio(0);
        __builtin_amdgcn_s_barrier();

#pragma unroll
        for (int j = 2; j < 4; ++j) {
            bhv[j] = *(const short8*)(Lc + 2 * OPS_ + boff + j * 512);
            blv[j] = *(const short8*)(Lc + 3 * OPS_ + boff + j * 512);
        }
        __builtin_amdgcn_s_barrier();
        asm volatile("s_waitcnt lgkmcnt(0)" ::: "memory");
        __builtin_amdgcn_sched_barrier(0);
        __builtin_amdgcn_s_setprio(1);
        QUAD(0, 1)
        __builtin_amdgcn_s_setprio(0);
        __builtin_amdgcn_s_barrier();

#pragma unroll
        for (int i = 0; i < 4; ++i) {
            ah[i] = *(const short8*)(Lc + aoff + 2048 + i * 512);
            al[i] = *(const short8*)(Lc + OPS_ + aoff + 2048 + i * 512);
        }
        __builtin_amdgcn_s_barrier();
        asm volatile("s_waitcnt lgkmcnt(0)" ::: "memory");
        __builtin_amdgcn_sched_barrier(0);
        __builtin_amdgcn_s_setprio(1);
        QUAD(1, 1)
        __builtin_amdgcn_s_setprio(0);
        __builtin_amdgcn_s_barrier();

        if (t + 2 < nt) STAGE8((t + 2) * 32, cur)
        __builtin_amdgcn_s_barrier();
        __builtin_amdgcn_s_setprio(1);
        QUAD(1, 0)
        __builtin_amdgcn_s_setprio(0);
        if (t + 2 < nt) {
            asm volatile("s_waitcnt vmcnt(8)" ::: "memory");
        } else if (t + 1 < nt) {
            asm volatile("s_waitcnt vmcnt(0)" ::: "memory");
        }
        __builtin_amdgcn_sched_barrier(0);
        __builtin_amdgcn_s_barrier();
    }
#undef STAGE8
#undef QUAD
}

// ---------------------------------------------------------------------------
// gemm_P: Ph/Pl[c][k*D+j] = split( sum_i class[c,i] * M[i,j,k] )
// ---------------------------------------------------------------------------
__launch_bounds__(512, 2)
__global__ void gemm_P_mfma8(const unsigned short* __restrict__ Chh,
                             const unsigned short* __restrict__ Cll,
                             const unsigned short* __restrict__ Mh,
                             const unsigned short* __restrict__ Ml,
                             unsigned short* __restrict__ Ph,
                             unsigned short* __restrict__ Pl) {
    __shared__ __attribute__((aligned(16))) unsigned short Lds[2 * BUFS_];
    f32x4 acc[8][4] = {};
    const int n0 = blockIdx.x * 256;   // over K*D
    const int c0 = blockIdx.y * 256;
    mfma_core8(Chh, Cll, Mh, Ml, D_, D_, D_, c0, n0, Lds, acc);
    const int lane = threadIdx.x & 63;
    const int wid = threadIdx.x >> 6;
    const int fr = lane & 15, fq = lane >> 4;
    const int wm = (wid >> 2) * 128, wn = (wid & 3) * 64;
#pragma unroll
    for (int mi = 0; mi < 8; ++mi)
#pragma unroll
        for (int ni = 0; ni < 4; ++ni)
#pragma unroll
            for (int r = 0; r < 4; ++r) {
                int c = c0 + wm + mi * 16 + fq * 4 + r;
                int n2 = n0 + wn + ni * 16 + fr;
                size_t o = (size_t)c * (K_ * D_) + n2;
                split2(acc[mi][ni][r], Ph[o], Pl[o]);
            }
}

// ---------------------------------------------------------------------------
// gemm_qf (split-K=8 over grid.z): qfp[z][q][d] = sum_{c in eighth} probs*classT
// ---------------------------------------------------------------------------
__launch_bounds__(512, 2)
__global__ void gemm_qf_mfma8(const unsigned short* __restrict__ Sh,
                              const unsigned short* __restrict__ Sl,
                              const unsigned short* __restrict__ Th,
                              const unsigned short* __restrict__ Tl,
                              float* __restrict__ qfp_base) {
    __shared__ __attribute__((aligned(16))) unsigned short Lds[2 * BUFS_];
    f32x4 acc[8][4] = {};
    const int n0 = blockIdx.x * 256;   // over D
    const int q0 = blockIdx.y * 256;
    const int zoff = blockIdx.z * (C_ / 8);
    float* qfp = qfp_base + (size_t)blockIdx.z * Q_ * D_;
    mfma_core8(Sh + zoff, Sl + zoff, Th + zoff, Tl + zoff,
               C_, C_, C_ / 8, q0, n0, Lds, acc);
    const int lane = threadIdx.x & 63;
    const int wid = threadIdx.x >> 6;
    const int fr = lane & 15, fq = lane >> 4;
    const int wm = (wid >> 2) * 128, wn = (wid & 3) * 64;
#pragma unroll
    for (int mi = 0; mi < 8; ++mi)
#pragma unroll
        for (int ni = 0; ni < 4; ++ni)
#pragma unroll
            for (int r = 0; r < 4; ++r) {
                int q = q0 + wm + mi * 16 + fq * 4 + r;
                int d = n0 + wn + ni * 16 + fr;
                qfp[(size_t)q * D_ + d] = acc[mi][ni][r];
            }
}

// ---------------------------------------------------------------------------
// Fused: softmax rows (blocks 0..4095) + classT transpose tiles (4096..4607).
// ---------------------------------------------------------------------------
__launch_bounds__(256)
__global__ void fused_softmax_tc(const float* __restrict__ other,
                                 unsigned short* __restrict__ Sh,
                                 unsigned short* __restrict__ Sl,
                                 const float* __restrict__ class_v,
                                 unsigned short* __restrict__ Th,
                                 unsigned short* __restrict__ Tl) {
    __shared__ float smem[64 * 65];
    const int b = blockIdx.x;
    const int tid = threadIdx.x;
    if (b < 4096) {
        const int q = b;
        const float* row = other + (size_t)q * C_;
        float v[16];
        float m = -1e30f;
#pragma unroll
        for (int it = 0; it < 16; ++it) {
            v[it] = row[tid + it * 256];
            m = fmaxf(m, v[it]);
        }
#pragma unroll
        for (int off = 32; off; off >>= 1) m = fmaxf(m, __shfl_down(m, off));
        if ((tid & 63) == 0) smem[tid >> 6] = m;
        __syncthreads();
        m = fmaxf(fmaxf(smem[0], smem[1]), fmaxf(smem[2], smem[3]));
        __syncthreads();
        float s = 0.f;
#pragma unroll
        for (int it = 0; it < 16; ++it) {
            v[it] = __expf(v[it] - m);
            s += v[it];
        }
#pragma unroll
        for (int off = 32; off; off >>= 1) s += __shfl_down(s, off);
        if ((tid & 63) == 0) smem[tid >> 6] = s;
        __syncthreads();
        const float inv = 1.f / (smem[0] + smem[1] + smem[2] + smem[3]);
#pragma unroll
        for (int it = 0; it < 16; ++it) {
            size_t o = (size_t)q * C_ + tid + it * 256;
            split2(v[it] * inv, Sh[o], Sl[o]);
        }
    } else {
        const int bb = b - 4096;
        const int c0 = (bb & 63) * 64;
        const int d0 = (bb >> 6) * 64;
#pragma unroll
        for (int it = 0; it < 16; ++it) {
            int idx = tid + it * 256;
            int rc = idx >> 6, dc = idx & 63;
            smem[dc * 65 + rc] = class_v[(size_t)(c0 + rc) * 512 + d0 + dc];
        }
        __syncthreads();
#pragma unroll
        for (int it = 0; it < 16; ++it) {
            int odx = tid + it * 256;
            int dr = odx >> 6, cc = odx & 63;
            size_t o = (size_t)(d0 + dr) * 4096 + c0 + cc;
            split2(smem[dr * 65 + cc], Th[o], Tl[o]);
        }
    }
}

// ---------------------------------------------------------------------------
// hash[q][l] = tanh( sum_d (sum_z qfp[z] + query)[q][d]*hash_w[l][d] + hb[l] )
// ---------------------------------------------------------------------------
__launch_bounds__(256)
__global__ void hash_kernel(const float* __restrict__ qfp_base,
                            const float* __restrict__ Qv,
                            const float* __restrict__ hw,
                            const float* __restrict__ hb,
                            float* __restrict__ out) {
    __shared__ float sqf[4 * D_];
    const int q0 = blockIdx.x * 4;
    const int tid = threadIdx.x;
    {
        const float4* sq = (const float4*)&Qv[(size_t)q0 * D_];
        float4* dst = (float4*)sqf;
#pragma unroll
        for (int it = 0; it < 2; ++it) {
            int i = tid + it * 256;
            float4 o = sq[i];
#pragma unroll
            for (int z = 0; z < 8; ++z) {
                const float4 a =
                    ((const float4*)&qfp_base[(size_t)z * Q_ * D_ + (size_t)q0 * D_])[i];
                o.x += a.x; o.y += a.y; o.z += a.z; o.w += a.w;
            }
            dst[i] = o;
        }
    }
    __syncthreads();
    const int l = tid % L_;
    const int qi = tid / L_;
    float s = hb[l];
    const float* wrow = &hw[(size_t)l * D_];
    const float* xrow = &sqf[qi * D_];
#pragma unroll 4
    for (int d = 0; d < D_; d += 4) {
        float4 w4 = *(const float4*)&wrow[d];
        float4 x4 = *(const float4*)&xrow[d];
        s += x4.x * w4.x + x4.y * w4.y + x4.z * w4.z + x4.w * w4.w;
    }
    out[(size_t)(q0 + qi) * L_ + l] = tanhf(s);
}

// ---------------------------------------------------------------------------
extern "C" void kernel_launch(void* const* d_in, const int* in_sizes, int n_in,
                              void* d_out, int out_size, void* d_ws, size_t ws_size,
                              hipStream_t stream) {
    const float* class_v = (const float*)d_in[0];
    const float* query_v = (const float*)d_in[1];
    const float* M       = (const float*)d_in[2];
    const float* score_w = (const float*)d_in[3];
    const float* score_b = (const float*)d_in[4];
    const float* hash_w  = (const float*)d_in[5];
    const float* hash_b  = (const float*)d_in[6];
    float* out = (float*)d_out;

    // Workspace (142.6 MB):
    //  [0,     33.5M)  Ph            -> Sh (probs hi) after softmax
    //  [33.5M, 67M)    Pl            -> Sl (probs lo)
    //  [67M,   134.2M) other (fp32 Q*C logits)
    //                  prep aliases (dead once bilinear writes other):
    //                    Mh/Ml at +0/+4.2M, Ch/Cl at +8.4M/+12.6M
    //                  post-softmax alias: qfp[8] at +0 (8 x 8.39M fp32 = 64MiB)
    //  [134.2M,142.6M) scratch: Qh/Ql (bf16)  -> Th/Tl (classT) after bilinear
    char* base = (char*)d_ws;
    unsigned short* Ph = (unsigned short*)base;
    unsigned short* Pl = (unsigned short*)(base + (size_t)33554432);
    char* oreg          = base + (size_t)67108864;
    float* other        = (float*)oreg;
    unsigned short* Mh  = (unsigned short*)oreg;
    unsigned short* Ml  = (unsigned short*)(oreg + (size_t)4194304);
    unsigned short* Chh = (unsigned short*)(oreg + (size_t)8388608);
    unsigned short* Cll = (unsigned short*)(oreg + (size_t)12582912);
    float* qfp          = (float*)oreg;
    char* scratch = base + (size_t)134217728;
    unsigned short* Qh = (unsigned short*)scratch;
    unsigned short* Ql = (unsigned short*)(scratch + (size_t)4194304);
    unsigned short* Th = (unsigned short*)scratch;
    unsigned short* Tl = (unsigned short*)(scratch + (size_t)4194304);
    unsigned short* Sh = Ph;
    unsigned short* Sl = Pl;

    fused_prep<<<4608, 256, 0, stream>>>(M, class_v, query_v, Mh, Ml, Chh, Cll, Qh, Ql);
    gemm_P_mfma8<<<dim3((K_ * D_) / 256, C_ / 256), 512, 0, stream>>>(Chh, Cll, Mh, Ml, Ph, Pl);
    bilinear_mfma<<<dim3(Q_ / BM1, N_ / BN1), 256, 0, stream>>>(Qh, Ql, Ph, Pl,
                                                                score_w, score_b, other);
    fused_softmax_tc<<<4608, 256, 0, stream>>>(other, Sh, Sl, class_v, Th, Tl);
    gemm_qf_mfma8<<<dim3(D_ / 256, Q_ / 256, 8), 512, 0, stream>>>(Sh, Sl, Th, Tl, qfp);
    hash_kernel<<<Q_ / 4, 256, 0, stream>>>(qfp, query_v, hash_w, hash_b, out);
}

// Round 10
// 656.933 us; speedup vs baseline: 1.3657x; 1.3657x over previous
//
#include <hip/hip_runtime.h>
#include <hip/hip_bf16.h>
#include <math.h>

#define D_ 512
#define K_ 8
#define L_ 64
#define Q_ 4096
#define C_ 4096
#define N_ (C_ * K_)   // 32768 rows of P viewed as [N][D]

typedef short short8 __attribute__((ext_vector_type(8)));
typedef float f32x4 __attribute__((ext_vector_type(4)));

static __device__ __forceinline__ void split2(float v, unsigned short& h, unsigned short& l) {
    __hip_bfloat16 hh = __float2bfloat16(v);
    float r = v - __bfloat162float(hh);
    __hip_bfloat16 ll = __float2bfloat16(r);
    h = *reinterpret_cast<unsigned short*>(&hh);
    l = *reinterpret_cast<unsigned short*>(&ll);
}

#define ASYNC_COPY16(gp, lp)                                                        \
    __builtin_amdgcn_global_load_lds((const __attribute__((address_space(1))) void*)(gp), \
                                     (__attribute__((address_space(3))) void*)(lp), \
                                     16, 0, 0)

// ---------------------------------------------------------------------------
// Fused prep: M-transpose tiles (blocks 0..511), class split x4 (512..2559),
// query split x4 (2560..4607). All fp32 -> bf16 hi/lo.
// ---------------------------------------------------------------------------
__global__ void fused_prep(const float* __restrict__ M,
                           const float* __restrict__ class_v,
                           const float* __restrict__ query_v,
                           unsigned short* __restrict__ Mh, unsigned short* __restrict__ Ml,
                           unsigned short* __restrict__ Chh, unsigned short* __restrict__ Cll,
                           unsigned short* __restrict__ Qh, unsigned short* __restrict__ Ql) {
    __shared__ float t[64 * 65];
    const int b = blockIdx.x;
    const int tid = threadIdx.x;
    if (b < 512) {
        // M [512 i][4096 t] (t=j*8+k) -> Mh/Ml [k*512+j][i]
        const int t0 = (b & 63) * 64;
        const int i0 = (b >> 6) * 64;
#pragma unroll
        for (int it = 0; it < 16; ++it) {
            int idx = tid + it * 256;
            int ri = idx >> 6, tc = idx & 63;
            t[tc * 65 + ri] = M[(size_t)(i0 + ri) * 4096 + t0 + tc];
        }
        __syncthreads();
        const int j0 = t0 >> 3;
#pragma unroll
        for (int it = 0; it < 16; ++it) {
            int odx = tid + it * 256;
            int tl = odx >> 6, ic = odx & 63;
            int n2 = (tl & 7) * 512 + j0 + (tl >> 3);
            size_t o = (size_t)n2 * 512 + i0 + ic;
            split2(t[tl * 65 + ic], Mh[o], Ml[o]);
        }
    } else if (b < 2560) {
        int i4 = ((b - 512) * 256 + tid) * 4;
        float4 v = *(const float4*)&class_v[i4];
        ushort4 h, l;
        split2(v.x, h.x, l.x);
        split2(v.y, h.y, l.y);
        split2(v.z, h.z, l.z);
        split2(v.w, h.w, l.w);
        *(ushort4*)&Chh[i4] = h;
        *(ushort4*)&Cll[i4] = l;
    } else {
        int i4 = ((b - 2560) * 256 + tid) * 4;
        float4 v = *(const float4*)&query_v[i4];
        ushort4 h, l;
        split2(v.x, h.x, l.x);
        split2(v.y, h.y, l.y);
        split2(v.z, h.z, l.z);
        split2(v.w, h.w, l.w);
        *(ushort4*)&Qh[i4] = h;
        *(ushort4*)&Ql[i4] = l;
    }
}

// ---------------------------------------------------------------------------
// 128x128 NT-GEMM core, counted-vmcnt schedule (r3/r8 measured-best).
// A via double-buffered LDS (global_load_lds, swizzled source); B direct
// global->VGPR with plain C++ loads. Per iter: stage A(t+1)->nxt then load
// B(t+1); MFMA on cur; end: vmcnt(4) (A landed, B in flight) + s_barrier.
// No vmcnt(0) in the main loop. bf16x3 term-reordered.
// ---------------------------------------------------------------------------
#define BM1 128
#define BN1 128
#define BNW1 32
#define BKK1 32

__device__ __forceinline__ void mfma_core_nt(
    const unsigned short* __restrict__ Agh, const unsigned short* __restrict__ Agl,
    const unsigned short* __restrict__ Bgh, const unsigned short* __restrict__ Bgl,
    int lda, int ldb, int kd, int m0, int n0,
    unsigned short (*Ahb)[BM1 * BKK1], unsigned short (*Alb)[BM1 * BKK1],
    f32x4 acc[8][2]) {
    const int tid = threadIdx.x;
    const int lane = tid & 63;
    const int wid = tid >> 6;
    const int fr = lane & 15;
    const int fq = lane >> 4;
    const int co = (fq ^ ((fr >> 1) & 3)) * 8;

    const unsigned short* bh0 = Bgh + (size_t)(n0 + wid * BNW1 + fr) * ldb + fq * 8;
    const unsigned short* bl0 = Bgl + (size_t)(n0 + wid * BNW1 + fr) * ldb + fq * 8;

    short8 bh[2][2], bl[2][2];

#define STAGE_A(k0_, buf_)                                                      \
    {                                                                           \
        _Pragma("unroll")                                                       \
        for (int h = 0; h < 2; ++h) {                                           \
            const int i2 = h * 256 + tid;                                       \
            const int r = i2 >> 2;                                              \
            const int cg = (i2 & 3) ^ ((r >> 1) & 3);                           \
            const int ldsoff = (h * 256 + (tid & ~63)) * 8;                     \
            const size_t go = (size_t)(m0 + r) * lda + (k0_) + cg * 8;          \
            ASYNC_COPY16(Agh + go, &Ahb[buf_][ldsoff]);                         \
            ASYNC_COPY16(Agl + go, &Alb[buf_][ldsoff]);                         \
        }                                                                       \
    }
#define LOAD_B(k0_, g_)                                                         \
    bh[g_][0] = *(const short8*)(bh0 + (k0_));                                  \
    bh[g_][1] = *(const short8*)(bh0 + 16 * (size_t)ldb + (k0_));               \
    bl[g_][0] = *(const short8*)(bl0 + (k0_));                                  \
    bl[g_][1] = *(const short8*)(bl0 + 16 * (size_t)ldb + (k0_));

    const int niter = kd / BKK1;   // 16 (kd inlined constant)

    // Prologue: stage A(0)->buf0 (issue FIRST), then B(0).
    STAGE_A(0, 0)
    asm volatile("" ::: "memory");   // pin issue order: A-stage before B-loads
    LOAD_B(0, 0)
    asm volatile("s_waitcnt vmcnt(4)" ::: "memory");   // A(0) in LDS; B(0) in flight
    __builtin_amdgcn_sched_barrier(0);
    asm volatile("s_barrier" ::: "memory");

#pragma unroll
    for (int it = 0; it < niter; ++it) {
        const int cur = it & 1, nxt = cur ^ 1;
        if (it + 1 < niter) {
            STAGE_A((it + 1) * BKK1, nxt)
        }
        asm volatile("" ::: "memory");   // pin issue order: A-stage before B-loads
        if (it + 1 < niter) {
            LOAD_B((it + 1) * BKK1, nxt)
        }
#pragma unroll
        for (int mi = 0; mi < 8; ++mi) {
            const short8 ah = *(const short8*)&Ahb[cur][(mi * 16 + fr) * BKK1 + co];
            const short8 al = *(const short8*)&Alb[cur][(mi * 16 + fr) * BKK1 + co];
#pragma unroll
            for (int ni = 0; ni < 2; ++ni)
                acc[mi][ni] = __builtin_amdgcn_mfma_f32_16x16x32_bf16(ah, bh[cur][ni], acc[mi][ni], 0, 0, 0);
#pragma unroll
            for (int ni = 0; ni < 2; ++ni)
                acc[mi][ni] = __builtin_amdgcn_mfma_f32_16x16x32_bf16(ah, bl[cur][ni], acc[mi][ni], 0, 0, 0);
#pragma unroll
            for (int ni = 0; ni < 2; ++ni)
                acc[mi][ni] = __builtin_amdgcn_mfma_f32_16x16x32_bf16(al, bh[cur][ni], acc[mi][ni], 0, 0, 0);
        }
        if (it + 1 < niter) {
            // A(it+1) (oldest 4 outstanding) landed; B(it+1) stays in flight.
            asm volatile("s_waitcnt vmcnt(4)" ::: "memory");
            __builtin_amdgcn_sched_barrier(0);
            asm volatile("s_barrier" ::: "memory");
        }
    }
#undef STAGE_A
#undef LOAD_B
}

// ---------------------------------------------------------------------------
// bilinear: other[q][c] = sb + sum_k sw[k]*relu( sum_j query[q,j]*P[c*8+k][j] )
// Natural grid order (q-fastest): 32 consecutive blocks share one B-panel.
// launch_bounds (256,4): HARD occupancy cap — 64 VGPR + 64 AGPR = 128
// regs/wave on the unified file; (256,5) forces spill (r9: WRITE 604 MB,
// 691 us). 4 blocks/CU is the register-bound maximum for this tile.
// ---------------------------------------------------------------------------
__launch_bounds__(256, 4)
__global__ void bilinear_mfma(const unsigned short* __restrict__ Qh,
                              const unsigned short* __restrict__ Ql,
                              const unsigned short* __restrict__ Ph,
                              const unsigned short* __restrict__ Pl,
                              const float* __restrict__ sw,
                              const float* __restrict__ sb,
                              float* __restrict__ other) {
    __shared__ __attribute__((aligned(16))) unsigned short Ahb[2][BM1 * BKK1];
    __shared__ __attribute__((aligned(16))) unsigned short Alb[2][BM1 * BKK1];
    const int tid = threadIdx.x;
    const int lane = tid & 63;
    const int wid = tid >> 6;
    const int fr = lane & 15;
    const int fq = lane >> 4;
    f32x4 acc[8][2] = {};
    const int q0 = blockIdx.x * BM1;   // q-fastest
    const int n0 = blockIdx.y * BN1;   // over N = C*K
    mfma_core_nt(Qh, Ql, Ph, Pl, D_, D_, D_, q0, n0, Ahb, Alb, acc);
    const float wk = sw[lane & 7];
    const float bias = sb[0];
#pragma unroll
    for (int mi = 0; mi < 8; ++mi)
#pragma unroll
        for (int ni = 0; ni < 2; ++ni)
#pragma unroll
            for (int r = 0; r < 4; ++r) {
                float v2 = wk * fmaxf(acc[mi][ni][r], 0.f);
                v2 += __shfl_xor(v2, 1);
                v2 += __shfl_xor(v2, 2);
                v2 += __shfl_xor(v2, 4);
                if ((lane & 7) == 0) {
                    int q = q0 + mi * 16 + fq * 4 + r;
                    int c = (n0 + wid * BNW1 + ni * 16 + fr) >> 3;
                    other[(size_t)q * C_ + c] = v2 + bias;
                }
            }
}

// ---------------------------------------------------------------------------
// 8-phase 256x256 MFMA NT-GEMM core (for the small L2-resident GEMMs).
// ---------------------------------------------------------------------------
#define OPS_ 8192
#define BUFS_ (4 * OPS_)

__device__ __forceinline__ void mfma_core8(
    const unsigned short* __restrict__ Agh, const unsigned short* __restrict__ Agl,
    const unsigned short* __restrict__ Bgh, const unsigned short* __restrict__ Bgl,
    const int lda, const int ldb, const int kd, const int m0, const int n0,
    unsigned short* Lds, f32x4 acc[8][4]) {
    const int tid = threadIdx.x;
    const int lane = tid & 63;
    const int wid = tid >> 6;
    const int fr = lane & 15;
    const int co = ((lane >> 4) ^ ((fr >> 1) & 3)) * 8;
    const int wm = (wid >> 2) * 128;
    const int wn = (wid & 3) * 64;
    const int nt = kd >> 5;
    const int aoff = (wm + fr) * 32 + co;
    const int boff = (wn + fr) * 32 + co;

#define STAGE8(k0_, buf_)                                                              \
    {                                                                                  \
        _Pragma("unroll")                                                              \
        for (int h_ = 0; h_ < 2; ++h_) {                                               \
            const int i2_ = h_ * 512 + tid;                                            \
            const int r_ = i2_ >> 2;                                                   \
            const int cg_ = (i2_ & 3) ^ ((r_ >> 1) & 3);                               \
            unsigned short* lp_ = Lds + (buf_) * BUFS_ + (h_ * 512 + (tid & ~63)) * 8; \
            const size_t ga_ = (size_t)(m0 + r_) * lda + (k0_) + cg_ * 8;              \
            const size_t gb_ = (size_t)(n0 + r_) * ldb + (k0_) + cg_ * 8;              \
            ASYNC_COPY16(Agh + ga_, lp_);                                              \
            ASYNC_COPY16(Agl + ga_, lp_ + OPS_);                                       \
            ASYNC_COPY16(Bgh + gb_, lp_ + 2 * OPS_);                                   \
            ASYNC_COPY16(Bgl + gb_, lp_ + 3 * OPS_);                                   \
        }                                                                              \
    }

#define QUAD(MH, NH)                                                                         \
    _Pragma("unroll")                                                                        \
    for (int i_ = 0; i_ < 4; ++i_) {                                                         \
        _Pragma("unroll")                                                                    \
        for (int j_ = 0; j_ < 2; ++j_) {                                                     \
            f32x4& a_ = acc[(MH) * 4 + i_][(NH) * 2 + j_];                                   \
            a_ = __builtin_amdgcn_mfma_f32_16x16x32_bf16(ah[i_], bhv[(NH) * 2 + j_], a_, 0, 0, 0); \
        }                                                                                    \
    }                                                                                        \
    _Pragma("unroll")                                                                        \
    for (int i_ = 0; i_ < 4; ++i_) {                                                         \
        _Pragma("unroll")                                                                    \
        for (int j_ = 0; j_ < 2; ++j_) {                                                     \
            f32x4& a_ = acc[(MH) * 4 + i_][(NH) * 2 + j_];                                   \
            a_ = __builtin_amdgcn_mfma_f32_16x16x32_bf16(ah[i_], blv[(NH) * 2 + j_], a_, 0, 0, 0); \
        }                                                                                    \
    }                                                                                        \
    _Pragma("unroll")                                                                        \
    for (int i_ = 0; i_ < 4; ++i_) {                                                         \
        _Pragma("unroll")                                                                    \
        for (int j_ = 0; j_ < 2; ++j_) {                                                     \
            f32x4& a_ = acc[(MH) * 4 + i_][(NH) * 2 + j_];                                   \
            a_ = __builtin_amdgcn_mfma_f32_16x16x32_bf16(al[i_], bhv[(NH) * 2 + j_], a_, 0, 0, 0); \
        }                                                                                    \
    }

    STAGE8(0, 0)
    STAGE8(32, 1)
    asm volatile("s_waitcnt vmcnt(8)" ::: "memory");
    __builtin_amdgcn_sched_barrier(0);
    __builtin_amdgcn_s_barrier();

#pragma unroll 2
    for (int t = 0; t < nt; ++t) {
        const int cur = t & 1;
        const unsigned short* Lc = Lds + cur * BUFS_;
        short8 ah[4], al[4], bhv[4], blv[4];

#pragma unroll
        for (int i = 0; i < 4; ++i) {
            ah[i] = *(const short8*)(Lc + aoff + i * 512);
            al[i] = *(const short8*)(Lc + OPS_ + aoff + i * 512);
        }
#pragma unroll
        for (int j = 0; j < 2; ++j) {
            bhv[j] = *(const short8*)(Lc + 2 * OPS_ + boff + j * 512);
            blv[j] = *(const short8*)(Lc + 3 * OPS_ + boff + j * 512);
        }
        __builtin_amdgcn_s_barrier();
        asm volatile("s_waitcnt lgkmcnt(0)" ::: "memory");
        __builtin_amdgcn_sched_barrier(0);
        __builtin_amdgcn_s_setprio(1);
        QUAD(0, 0)
        __builtin_amdgcn_s_setprio(0);
        __builtin_amdgcn_s_barrier();

#pragma unroll
        for (int j = 2; j < 4; ++j) {
            bhv[j] = *(const short8*)(Lc + 2 * OPS_ + boff + j * 512);
            blv[j] = *(const short8*)(Lc + 3 * OPS_ + boff + j * 512);
        }
        __builtin_amdgcn_s_barrier();
        asm volatile("s_waitcnt lgkmcnt(0)" ::: "memory");
        __builtin_amdgcn_sched_barrier(0);
        __builtin_amdgcn_s_setprio(1);
        QUAD(0, 1)
        __builtin_amdgcn_s_setprio(0);
        __builtin_amdgcn_s_barrier();

#pragma unroll
        for (int i = 0; i < 4; ++i) {
            ah[i] = *(const short8*)(Lc + aoff + 2048 + i * 512);
            al[i] = *(const short8*)(Lc + OPS_ + aoff + 2048 + i * 512);
        }
        __builtin_amdgcn_s_barrier();
        asm volatile("s_waitcnt lgkmcnt(0)" ::: "memory");
        __builtin_amdgcn_sched_barrier(0);
        __builtin_amdgcn_s_setprio(1);
        QUAD(1, 1)
        __builtin_amdgcn_s_setprio(0);
        __builtin_amdgcn_s_barrier();

        if (t + 2 < nt) STAGE8((t + 2) * 32, cur)
        __builtin_amdgcn_s_barrier();
        __builtin_amdgcn_s_setprio(1);
        QUAD(1, 0)
        __builtin_amdgcn_s_setprio(0);
        if (t + 2 < nt) {
            asm volatile("s_waitcnt vmcnt(8)" ::: "memory");
        } else if (t + 1 < nt) {
            asm volatile("s_waitcnt vmcnt(0)" ::: "memory");
        }
        __builtin_amdgcn_sched_barrier(0);
        __builtin_amdgcn_s_barrier();
    }
#undef STAGE8
#undef QUAD
}

// ---------------------------------------------------------------------------
// gemm_P: Ph/Pl[c][k*D+j] = split( sum_i class[c,i] * M[i,j,k] )
// ---------------------------------------------------------------------------
__launch_bounds__(512, 2)
__global__ void gemm_P_mfma8(const unsigned short* __restrict__ Chh,
                             const unsigned short* __restrict__ Cll,
                             const unsigned short* __restrict__ Mh,
                             const unsigned short* __restrict__ Ml,
                             unsigned short* __restrict__ Ph,
                             unsigned short* __restrict__ Pl) {
    __shared__ __attribute__((aligned(16))) unsigned short Lds[2 * BUFS_];
    f32x4 acc[8][4] = {};
    const int n0 = blockIdx.x * 256;   // over K*D
    const int c0 = blockIdx.y * 256;
    mfma_core8(Chh, Cll, Mh, Ml, D_, D_, D_, c0, n0, Lds, acc);
    const int lane = threadIdx.x & 63;
    const int wid = threadIdx.x >> 6;
    const int fr = lane & 15, fq = lane >> 4;
    const int wm = (wid >> 2) * 128, wn = (wid & 3) * 64;
#pragma unroll
    for (int mi = 0; mi < 8; ++mi)
#pragma unroll
        for (int ni = 0; ni < 4; ++ni)
#pragma unroll
            for (int r = 0; r < 4; ++r) {
                int c = c0 + wm + mi * 16 + fq * 4 + r;
                int n2 = n0 + wn + ni * 16 + fr;
                size_t o = (size_t)c * (K_ * D_) + n2;
                split2(acc[mi][ni][r], Ph[o], Pl[o]);
            }
}

// ---------------------------------------------------------------------------
// gemm_qf (split-K=8 over grid.z): qfp[z][q][d] = sum_{c in eighth} probs*classT
// ---------------------------------------------------------------------------
__launch_bounds__(512, 2)
__global__ void gemm_qf_mfma8(const unsigned short* __restrict__ Sh,
                              const unsigned short* __restrict__ Sl,
                              const unsigned short* __restrict__ Th,
                              const unsigned short* __restrict__ Tl,
                              float* __restrict__ qfp_base) {
    __shared__ __attribute__((aligned(16))) unsigned short Lds[2 * BUFS_];
    f32x4 acc[8][4] = {};
    const int n0 = blockIdx.x * 256;   // over D
    const int q0 = blockIdx.y * 256;
    const int zoff = blockIdx.z * (C_ / 8);
    float* qfp = qfp_base + (size_t)blockIdx.z * Q_ * D_;
    mfma_core8(Sh + zoff, Sl + zoff, Th + zoff, Tl + zoff,
               C_, C_, C_ / 8, q0, n0, Lds, acc);
    const int lane = threadIdx.x & 63;
    const int wid = threadIdx.x >> 6;
    const int fr = lane & 15, fq = lane >> 4;
    const int wm = (wid >> 2) * 128, wn = (wid & 3) * 64;
#pragma unroll
    for (int mi = 0; mi < 8; ++mi)
#pragma unroll
        for (int ni = 0; ni < 4; ++ni)
#pragma unroll
            for (int r = 0; r < 4; ++r) {
                int q = q0 + wm + mi * 16 + fq * 4 + r;
                int d = n0 + wn + ni * 16 + fr;
                qfp[(size_t)q * D_ + d] = acc[mi][ni][r];
            }
}

// ---------------------------------------------------------------------------
// Fused: softmax rows (blocks 0..4095) + classT transpose tiles (4096..4607).
// ---------------------------------------------------------------------------
__launch_bounds__(256)
__global__ void fused_softmax_tc(const float* __restrict__ other,
                                 unsigned short* __restrict__ Sh,
                                 unsigned short* __restrict__ Sl,
                                 const float* __restrict__ class_v,
                                 unsigned short* __restrict__ Th,
                                 unsigned short* __restrict__ Tl) {
    __shared__ float smem[64 * 65];
    const int b = blockIdx.x;
    const int tid = threadIdx.x;
    if (b < 4096) {
        const int q = b;
        const float* row = other + (size_t)q * C_;
        float v[16];
        float m = -1e30f;
#pragma unroll
        for (int it = 0; it < 16; ++it) {
            v[it] = row[tid + it * 256];
            m = fmaxf(m, v[it]);
        }
#pragma unroll
        for (int off = 32; off; off >>= 1) m = fmaxf(m, __shfl_down(m, off));
        if ((tid & 63) == 0) smem[tid >> 6] = m;
        __syncthreads();
        m = fmaxf(fmaxf(smem[0], smem[1]), fmaxf(smem[2], smem[3]));
        __syncthreads();
        float s = 0.f;
#pragma unroll
        for (int it = 0; it < 16; ++it) {
            v[it] = __expf(v[it] - m);
            s += v[it];
        }
#pragma unroll
        for (int off = 32; off; off >>= 1) s += __shfl_down(s, off);
        if ((tid & 63) == 0) smem[tid >> 6] = s;
        __syncthreads();
        const float inv = 1.f / (smem[0] + smem[1] + smem[2] + smem[3]);
#pragma unroll
        for (int it = 0; it < 16; ++it) {
            size_t o = (size_t)q * C_ + tid + it * 256;
            split2(v[it] * inv, Sh[o], Sl[o]);
        }
    } else {
        const int bb = b - 4096;
        const int c0 = (bb & 63) * 64;
        const int d0 = (bb >> 6) * 64;
#pragma unroll
        for (int it = 0; it < 16; ++it) {
            int idx = tid + it * 256;
            int rc = idx >> 6, dc = idx & 63;
            smem[dc * 65 + rc] = class_v[(size_t)(c0 + rc) * 512 + d0 + dc];
        }
        __syncthreads();
#pragma unroll
        for (int it = 0; it < 16; ++it) {
            int odx = tid + it * 256;
            int dr = odx >> 6, cc = odx & 63;
            size_t o = (size_t)(d0 + dr) * 4096 + c0 + cc;
            split2(smem[dr * 65 + cc], Th[o], Tl[o]);
        }
    }
}

// ---------------------------------------------------------------------------
// hash[q][l] = tanh( sum_d (sum_z qfp[z] + query)[q][d]*hash_w[l][d] + hb[l] )
// ---------------------------------------------------------------------------
__launch_bounds__(256)
__global__ void hash_kernel(const float* __restrict__ qfp_base,
                            const float* __restrict__ Qv,
                            const float* __restrict__ hw,
                            const float* __restrict__ hb,
                            float* __restrict__ out) {
    __shared__ float sqf[4 * D_];
    const int q0 = blockIdx.x * 4;
    const int tid = threadIdx.x;
    {
        const float4* sq = (const float4*)&Qv[(size_t)q0 * D_];
        float4* dst = (float4*)sqf;
#pragma unroll
        for (int it = 0; it < 2; ++it) {
            int i = tid + it * 256;
            float4 o = sq[i];
#pragma unroll
            for (int z = 0; z < 8; ++z) {
                const float4 a =
                    ((const float4*)&qfp_base[(size_t)z * Q_ * D_ + (size_t)q0 * D_])[i];
                o.x += a.x; o.y += a.y; o.z += a.z; o.w += a.w;
            }
            dst[i] = o;
        }
    }
    __syncthreads();
    const int l = tid % L_;
    const int qi = tid / L_;
    float s = hb[l];
    const float* wrow = &hw[(size_t)l * D_];
    const float* xrow = &sqf[qi * D_];
#pragma unroll 4
    for (int d = 0; d < D_; d += 4) {
        float4 w4 = *(const float4*)&wrow[d];
        float4 x4 = *(const float4*)&xrow[d];
        s += x4.x * w4.x + x4.y * w4.y + x4.z * w4.z + x4.w * w4.w;
    }
    out[(size_t)(q0 + qi) * L_ + l] = tanhf(s);
}

// ---------------------------------------------------------------------------
extern "C" void kernel_launch(void* const* d_in, const int* in_sizes, int n_in,
                              void* d_out, int out_size, void* d_ws, size_t ws_size,
                              hipStream_t stream) {
    const float* class_v = (const float*)d_in[0];
    const float* query_v = (const float*)d_in[1];
    const float* M       = (const float*)d_in[2];
    const float* score_w = (const float*)d_in[3];
    const float* score_b = (const float*)d_in[4];
    const float* hash_w  = (const float*)d_in[5];
    const float* hash_b  = (const float*)d_in[6];
    float* out = (float*)d_out;

    // Workspace (142.6 MB):
    //  [0,     33.5M)  Ph            -> Sh (probs hi) after softmax
    //  [33.5M, 67M)    Pl            -> Sl (probs lo)
    //  [67M,   134.2M) other (fp32 Q*C logits)
    //                  prep aliases (dead once bilinear writes other):
    //                    Mh/Ml at +0/+4.2M, Ch/Cl at +8.4M/+12.6M
    //                  post-softmax alias: qfp[8] at +0 (8 x 8.39M fp32 = 64MiB)
    //  [134.2M,142.6M) scratch: Qh/Ql (bf16)  -> Th/Tl (classT) after bilinear
    char* base = (char*)d_ws;
    unsigned short* Ph = (unsigned short*)base;
    unsigned short* Pl = (unsigned short*)(base + (size_t)33554432);
    char* oreg          = base + (size_t)67108864;
    float* other        = (float*)oreg;
    unsigned short* Mh  = (unsigned short*)oreg;
    unsigned short* Ml  = (unsigned short*)(oreg + (size_t)4194304);
    unsigned short* Chh = (unsigned short*)(oreg + (size_t)8388608);
    unsigned short* Cll = (unsigned short*)(oreg + (size_t)12582912);
    float* qfp          = (float*)oreg;
    char* scratch = base + (size_t)134217728;
    unsigned short* Qh = (unsigned short*)scratch;
    unsigned short* Ql = (unsigned short*)(scratch + (size_t)4194304);
    unsigned short* Th = (unsigned short*)scratch;
    unsigned short* Tl = (unsigned short*)(scratch + (size_t)4194304);
    unsigned short* Sh = Ph;
    unsigned short* Sl = Pl;

    fused_prep<<<4608, 256, 0, stream>>>(M, class_v, query_v, Mh, Ml, Chh, Cll, Qh, Ql);
    gemm_P_mfma8<<<dim3((K_ * D_) / 256, C_ / 256), 512, 0, stream>>>(Chh, Cll, Mh, Ml, Ph, Pl);
    bilinear_mfma<<<dim3(Q_ / BM1, N_ / BN1), 256, 0, stream>>>(Qh, Ql, Ph, Pl,
                                                                score_w, score_b, other);
    fused_softmax_tc<<<4608, 256, 0, stream>>>(other, Sh, Sl, class_v, Th, Tl);
    gemm_qf_mfma8<<<dim3(D_ / 256, Q_ / 256, 8), 512, 0, stream>>>(Sh, Sl, Th, Tl, qfp);
    hash_kernel<<<Q_ / 4, 256, 0, stream>>>(qfp, query_v, hash_w, hash_b, out);
}